// Round 6
// baseline (154.367 us; speedup 1.0000x reference)
//
#include <hip/hip_runtime.h>
#include <hip/hip_bf16.h>

typedef __hip_bfloat16 bf16;
typedef __attribute__((ext_vector_type(8))) short bf16x8;
typedef __attribute__((ext_vector_type(4))) float f32x4;
typedef __attribute__((ext_vector_type(4))) short s16x4;

constexpr int B_ = 2, N_ = 2048, E_ = 1024, H_ = 16, KD_ = 64;
constexpr int M_ = B_ * N_;                 // 4096 token rows
constexpr float SCALE = 0.25f * 1.44269504088896f;  // (1/4) * log2(e), folded into K

#define MFMA16(A, Bf, C) __builtin_amdgcn_mfma_f32_16x16x32_bf16(A, Bf, C, 0, 0, 0)
#define SBAR() do { __builtin_amdgcn_s_barrier(); __builtin_amdgcn_sched_barrier(0); } while (0)
#define WAITCNT(s) asm volatile("s_waitcnt " s ::: "memory")

typedef const __attribute__((address_space(1))) void* gptr_t;
typedef __attribute__((address_space(3))) void* sptr_t;

__device__ inline short bf16bits(float f) {
  bf16 h = __float2bfloat16(f);
  short s;
  __builtin_memcpy(&s, &h, 2);
  return s;
}
__device__ inline float bf16f(short s) {
  bf16 h;
  __builtin_memcpy(&h, &s, 2);
  return __bfloat162float(h);
}

// ---------------------------------------------------------------------------
// Stage 64 rows x 128 bytes (64 bf16/row) global->LDS, XOR-swizzled:
// logical (row, slot16) stored at byte  row*128 + ((slot16*16) ^ ((row&7)<<4)).
// Pre-swizzled SOURCE + linear global_load_lds dest (rule #21). 256 threads.
// 2 global_load_lds per thread per call.
// ---------------------------------------------------------------------------
__device__ inline void stage64(const bf16* __restrict__ base, int stride_elems,
                               char* lds) {
  const int t = threadIdx.x;
#pragma unroll
  for (int i = 0; i < 2; i++) {
    int L = i * 4096 + t * 16;                    // linear LDS byte offset
    int row = L >> 7;
    int slot = ((L >> 4) & 7) ^ (row & 7);        // inverse of the XOR swizzle
    const bf16* src = base + (size_t)row * stride_elems + slot * 8;
    __builtin_amdgcn_global_load_lds((gptr_t)(const void*)src,
                                     (sptr_t)(void*)(lds + L), 16, 0, 0);
  }
}

// Read one MFMA A/B fragment (8 bf16 along k) from a swizzled tile (128B rows).
__device__ inline bf16x8 frag_ld(const char* lds, int row, int ks) {
  const int g = (threadIdx.x >> 4) & 3;           // lane>>4 within wave
  const int off = (ks * 64 + g * 16) ^ ((row & 7) << 4);
  return *(const bf16x8*)(lds + row * 128 + off);
}

// ---------------------------------------------------------------------------
// Elementwise fp32 -> bf16 for x, Wq, Wk, Wv, Wp (contiguous dst).
// ---------------------------------------------------------------------------
__global__ __launch_bounds__(256) void cvt_all(
    const float* __restrict__ x, const float* __restrict__ wq,
    const float* __restrict__ wk, const float* __restrict__ wv,
    const float* __restrict__ wp, bf16* __restrict__ dst) {
  const size_t XN = (size_t)M_ * E_;              // 4M
  const size_t WN = (size_t)E_ * E_;              // 1M
  size_t i = ((size_t)blockIdx.x * 256 + threadIdx.x) * 4;
  const float* src;
  size_t off;
  if (i < XN) { src = x; off = i; }
  else if (i < XN + WN) { src = wq; off = i - XN; }
  else if (i < XN + 2 * WN) { src = wk; off = i - XN - WN; }
  else if (i < XN + 3 * WN) { src = wv; off = i - XN - 2 * WN; }
  else { src = wp; off = i - XN - 3 * WN; }
  float4 v = *(const float4*)(src + off);
  s16x4 o;
  o[0] = bf16bits(v.x); o[1] = bf16bits(v.y);
  o[2] = bf16bits(v.z); o[3] = bf16bits(v.w);
  *(s16x4*)(dst + i) = o;
}

// ---------------------------------------------------------------------------
// Fused QKV GEMM: [Q|K|V] = x @ Wqkv^T + b.  128x128 tile, BK=64, 4 waves.
// Q head-major; K head-major PRE-SCALED by (1/4)*log2(e); V transposed heads.
// ---------------------------------------------------------------------------
__global__ __launch_bounds__(256) void gemm_qkv(
    const bf16* __restrict__ A, const bf16* __restrict__ Wb,
    const float* __restrict__ bq, const float* __restrict__ bk,
    const float* __restrict__ bv, bf16* __restrict__ Qhd,
    bf16* __restrict__ Khd, bf16* __restrict__ Vtd) {
  __shared__ char Asm[16384];
  __shared__ char Bsm[16384];
  const int t = threadIdx.x, lane = t & 63, w = t >> 6;
  const int wr = w >> 1, wc = w & 1;
  const int c = lane & 15, g = lane >> 4;
  const int row0 = blockIdx.y * 128, col0 = blockIdx.x * 128;
  f32x4 acc[4][4] = {};

  for (int k0 = 0; k0 < E_; k0 += 64) {
    stage64(A + (size_t)row0 * E_ + k0, E_, Asm);
    stage64(A + (size_t)(row0 + 64) * E_ + k0, E_, Asm + 8192);
    stage64(Wb + (size_t)col0 * E_ + k0, E_, Bsm);
    stage64(Wb + (size_t)(col0 + 64) * E_ + k0, E_, Bsm + 8192);
    __syncthreads();
#pragma unroll
    for (int ks = 0; ks < 2; ks++) {
      bf16x8 af[4], bfr[4];
#pragma unroll
      for (int mi = 0; mi < 4; mi++) af[mi] = frag_ld(Asm, wr * 64 + mi * 16 + c, ks);
#pragma unroll
      for (int ni = 0; ni < 4; ni++) bfr[ni] = frag_ld(Bsm, wc * 64 + ni * 16 + c, ks);
#pragma unroll
      for (int mi = 0; mi < 4; mi++)
#pragma unroll
        for (int ni = 0; ni < 4; ni++)
          acc[mi][ni] = MFMA16(af[mi], bfr[ni], acc[mi][ni]);
    }
    __syncthreads();
  }

  const int sel = col0 >> 10;                     // 0:Q 1:K 2:V (uniform)
  const float* biasp = sel == 0 ? bq : sel == 1 ? bk : bv;
  bf16* outp = sel == 0 ? Qhd : sel == 1 ? Khd : Vtd;
#pragma unroll
  for (int mi = 0; mi < 4; mi++) {
#pragma unroll
    for (int ni = 0; ni < 4; ni++) {
      const int row = row0 + wr * 64 + mi * 16 + g * 4;
      const int col = col0 + wc * 64 + ni * 16 + c;
      const int ccol = col & 1023, h = ccol >> 6, kd = ccol & 63;
      const float bvf = biasp[ccol];
      if (sel < 2) {
        const float scl = (sel == 1) ? SCALE : 1.0f;
#pragma unroll
        for (int r = 0; r < 4; r++) {
          const int rr = row + r, b = rr >> 11, n = rr & (N_ - 1);
          outp[(((size_t)(b * H_ + h)) * N_ + n) * KD_ + kd] =
              __float2bfloat16((acc[mi][ni][r] + bvf) * scl);
        }
      } else {
        const int b = row >> 11, n = row & (N_ - 1);
        s16x4 o;
#pragma unroll
        for (int r = 0; r < 4; r++) o[r] = bf16bits(acc[mi][ni][r] + bvf);
        *(s16x4*)&outp[(((size_t)(b * H_ + h)) * KD_ + kd) * N_ + n] = o;
      }
    }
  }
}

// ---------------------------------------------------------------------------
// Projection GEMM: out(fp32) = attn @ Wp^T + bp.
// ---------------------------------------------------------------------------
__global__ __launch_bounds__(256) void gemm_proj(
    const bf16* __restrict__ A, const bf16* __restrict__ Wb,
    const float* __restrict__ bias, float* __restrict__ outf) {
  __shared__ char Asm[16384];
  __shared__ char Bsm[16384];
  const int t = threadIdx.x, lane = t & 63, w = t >> 6;
  const int wr = w >> 1, wc = w & 1;
  const int c = lane & 15, g = lane >> 4;
  const int row0 = blockIdx.y * 128, col0 = blockIdx.x * 128;
  f32x4 acc[4][4] = {};

  for (int k0 = 0; k0 < E_; k0 += 64) {
    stage64(A + (size_t)row0 * E_ + k0, E_, Asm);
    stage64(A + (size_t)(row0 + 64) * E_ + k0, E_, Asm + 8192);
    stage64(Wb + (size_t)col0 * E_ + k0, E_, Bsm);
    stage64(Wb + (size_t)(col0 + 64) * E_ + k0, E_, Bsm + 8192);
    __syncthreads();
#pragma unroll
    for (int ks = 0; ks < 2; ks++) {
      bf16x8 af[4], bfr[4];
#pragma unroll
      for (int mi = 0; mi < 4; mi++) af[mi] = frag_ld(Asm, wr * 64 + mi * 16 + c, ks);
#pragma unroll
      for (int ni = 0; ni < 4; ni++) bfr[ni] = frag_ld(Bsm, wc * 64 + ni * 16 + c, ks);
#pragma unroll
      for (int mi = 0; mi < 4; mi++)
#pragma unroll
        for (int ni = 0; ni < 4; ni++)
          acc[mi][ni] = MFMA16(af[mi], bfr[ni], acc[mi][ni]);
    }
    __syncthreads();
  }

#pragma unroll
  for (int mi = 0; mi < 4; mi++) {
#pragma unroll
    for (int ni = 0; ni < 4; ni++) {
      const int row = row0 + wr * 64 + mi * 16 + g * 4;
      const int col = col0 + wc * 64 + ni * 16 + c;
      const float bvf = bias[col];
#pragma unroll
      for (int r = 0; r < 4; r++)
        outf[(size_t)(row + r) * E_ + col] = acc[mi][ni][r] + bvf;
    }
  }
}

// ---------------------------------------------------------------------------
// Phase A: rowsum[m] = sum_{n<=m} exp(T[m,n]) (K pre-scaled), then scales
// Vt columns m by 1/rowsum in-place.  Diagonal-paired blocks; Q triple-
// buffered with depth-2 counted-vmcnt prefetch (raw s_barrier, no vmcnt(0)
// drain in the loop).  Per-tile load batch = 4 global_load_lds/thread.
// ---------------------------------------------------------------------------
__global__ __launch_bounds__(256) void phaseA(
    const bf16* __restrict__ Kh, const bf16* __restrict__ Qh,
    bf16* __restrict__ Vt) {
  __shared__ char Ksm[8192];
  __shared__ char Qsm[3][16384];
  __shared__ float rbuf[64];
  const int t = threadIdx.x, lane = t & 63, w = t >> 6;
  const int c = lane & 15, g = lane >> 4;
  const int bh = blockIdx.y;
  const bf16* Kb = Kh + (size_t)bh * N_ * KD_;
  const bf16* Qb = Qh + (size_t)bh * N_ * KD_;
  bf16* Vtb = Vt + (size_t)bh * KD_ * N_;

#pragma unroll 1
  for (int seg = 0; seg < 2; seg++) {
    const int mb = seg ? (31 - blockIdx.x) : blockIdx.x;  // 64-row m-block
    const int m0 = mb * 64;
    const int ntE = mb >> 1;                    // last (masked) 128-wide tile

    SBAR();                                     // prior-seg LDS reads done
    stage64(Kb + (size_t)m0 * KD_, KD_, Ksm);                  // 2 loads
    stage64(Qb, KD_, Qsm[0]);                                  // 4 loads
    stage64(Qb + (size_t)64 * KD_, KD_, Qsm[0] + 8192);
    if (ntE >= 1) {
      stage64(Qb + (size_t)128 * KD_, KD_, Qsm[1]);            // 4 loads
      stage64(Qb + (size_t)192 * KD_, KD_, Qsm[1] + 8192);
      WAITCNT("vmcnt(8)");                      // K done; Q0,Q1 in flight
    } else {
      WAITCNT("vmcnt(4)");                      // K done; Q0 in flight
    }
    SBAR();
    bf16x8 af0 = frag_ld(Ksm, w * 16 + c, 0);
    bf16x8 af1 = frag_ld(Ksm, w * 16 + c, 1);
    float sm[4] = {};

#pragma unroll 1
    for (int nt = 0; nt <= ntE; nt++) {
      // batch nt retired (FIFO: <=4 outstanding leaves only batch nt+1);
      // lgkmcnt(0): own ds ops (af/qf reads, prior writes) complete.
      if (nt + 1 <= ntE) WAITCNT("vmcnt(4) lgkmcnt(0)");
      else WAITCNT("vmcnt(0) lgkmcnt(0)");
      SBAR();
      if (nt + 2 <= ntE) {
        stage64(Qb + (size_t)(nt + 2) * 128 * KD_, KD_, Qsm[(nt + 2) % 3]);
        stage64(Qb + (size_t)((nt + 2) * 128 + 64) * KD_, KD_,
                Qsm[(nt + 2) % 3] + 8192);
      }
      const char* qs = Qsm[nt % 3];
      if (nt < ntE) {
#pragma unroll
        for (int ni = 0; ni < 8; ni++) {
          bf16x8 b0 = frag_ld(qs, ni * 16 + c, 0);
          bf16x8 b1 = frag_ld(qs, ni * 16 + c, 1);
          f32x4 s = {0.f, 0.f, 0.f, 0.f};
          s = MFMA16(af0, b0, s);
          s = MFMA16(af1, b1, s);
#pragma unroll
          for (int r = 0; r < 4; r++) sm[r] += exp2f(s[r]);
        }
      } else {
        const int mg = m0 + w * 16 + g * 4;     // m for r=0
#pragma unroll
        for (int ni = 0; ni < 8; ni++) {
          bf16x8 b0 = frag_ld(qs, ni * 16 + c, 0);
          bf16x8 b1 = frag_ld(qs, ni * 16 + c, 1);
          f32x4 s = {0.f, 0.f, 0.f, 0.f};
          s = MFMA16(af0, b0, s);
          s = MFMA16(af1, b1, s);
          const int ng = nt * 128 + ni * 16 + c;
#pragma unroll
          for (int r = 0; r < 4; r++) {
            float e = exp2f(s[r]);
            sm[r] += (ng <= mg + r) ? e : 0.f;
          }
        }
      }
    }

#pragma unroll
    for (int r = 0; r < 4; r++) {
      float v = sm[r];
#pragma unroll
      for (int d = 1; d < 16; d <<= 1) v += __shfl_xor(v, d, 64);
      if (c == 0) rbuf[w * 16 + g * 4 + r] = 1.0f / v;
    }
    WAITCNT("lgkmcnt(0)");
    SBAR();                                     // rbuf visible to all
    // scale Vt columns [m0, m0+64) in place: V'[kd][m] = V[kd][m]/rowsum[m]
#pragma unroll
    for (int pass = 0; pass < 2; pass++) {
      const int idx = pass * 256 + t;
      const int kd = idx >> 3, mc = idx & 7;
      bf16* p = Vtb + (size_t)kd * N_ + m0 + mc * 8;
      bf16x8 v = *(const bf16x8*)p;
      bf16x8 o;
#pragma unroll
      for (int j = 0; j < 8; j++) o[j] = bf16bits(bf16f(v[j]) * rbuf[mc * 8 + j]);
      *(bf16x8*)p = o;
    }
  }
}

// ---------------------------------------------------------------------------
// Phase B: out[n][kd] = sum_{m>=n} exp(T[m,n]) * V'[m][kd]  (V pre-divided by
// rowsum, K pre-scaled).  Diagonal-paired blocks (uniform 33 m-tiles).
// Depth-2 counted-vmcnt pipeline, PV lags one tile:
//   tile t: wait vmcnt(4)+lgkm0, s_barrier; issue KV(t+2); QK(t)->P[t&1];
//           PV(t-1) from P[(t-1)&1], V[(t-1)&3].
// K triple-, V quadruple-, P double-buffered (72 KB LDS, 2 blocks/CU).
// ---------------------------------------------------------------------------
__global__ __launch_bounds__(256) void phaseB(
    const bf16* __restrict__ Qh, const bf16* __restrict__ Kh,
    const bf16* __restrict__ Vt, bf16* __restrict__ attn) {
  __shared__ char Ksm[3][8192];
  __shared__ char Vsm[4][8192];
  __shared__ char Psm[2][8192];
  const int t = threadIdx.x, lane = t & 63, w = t >> 6;
  const int c = lane & 15, g = lane >> 4;
  const int bh = blockIdx.y, b = bh >> 4, h = bh & 15;
  const int NT = N_ / 64;
  const bf16* Qb = Qh + (size_t)bh * N_ * KD_;
  const bf16* Kb = Kh + (size_t)bh * N_ * KD_;
  const bf16* Vb = Vt + (size_t)bh * KD_ * N_;   // rows kd, stride N_

  auto qk_tile = [&](int mt, const bf16x8 (&qf)[4][2], bool diag) {
    const char* ks = Ksm[mt % 3];
    bf16x8 kf0 = frag_ld(ks, w * 16 + c, 0);
    bf16x8 kf1 = frag_ld(ks, w * 16 + c, 1);
    char* ps = Psm[mt & 1];
#pragma unroll
    for (int ni = 0; ni < 4; ni++) {
      f32x4 s = {0.f, 0.f, 0.f, 0.f};
      s = MFMA16(kf0, qf[ni][0], s);
      s = MFMA16(kf1, qf[ni][1], s);
      const int nloc = ni * 16 + c;
      s16x4 p;
#pragma unroll
      for (int r = 0; r < 4; r++) {
        float val = exp2f(s[r]);
        if (diag && nloc > (w * 16 + g * 4 + r)) val = 0.f;
        p[r] = bf16bits(val);
      }
      const int off = nloc * 128 + ((w * 32 + g * 8) ^ ((nloc & 7) << 4));
      *(s16x4*)(ps + off) = p;
    }
  };

  auto pv_tile = [&](int mt, f32x4 (&out)[4]) {
    const char* ps = Psm[mt & 1];
    const char* vs = Vsm[mt & 3];
    bf16x8 pa0 = frag_ld(ps, w * 16 + c, 0);
    bf16x8 pa1 = frag_ld(ps, w * 16 + c, 1);
#pragma unroll
    for (int ni = 0; ni < 4; ni++) {
      bf16x8 v0 = frag_ld(vs, ni * 16 + c, 0);
      bf16x8 v1 = frag_ld(vs, ni * 16 + c, 1);
      out[ni] = MFMA16(pa0, v0, out[ni]);
      out[ni] = MFMA16(pa1, v1, out[ni]);
    }
  };

#pragma unroll 1
  for (int seg = 0; seg < 2; seg++) {
    const int qt = seg ? (NT - 1 - blockIdx.x) : blockIdx.x;
    const int n0 = qt * 64, mt0 = qt;

    SBAR();                                     // prior-seg LDS reads done
    stage64(Qb + (size_t)n0 * KD_, KD_, Psm[0]);               // 2 loads
    stage64(Kb + (size_t)mt0 * 64 * KD_, KD_, Ksm[mt0 % 3]);   // 2
    stage64(Vb + mt0 * 64, N_, Vsm[mt0 & 3]);                  // 2
    if (mt0 + 1 < NT) {
      stage64(Kb + (size_t)(mt0 + 1) * 64 * KD_, KD_, Ksm[(mt0 + 1) % 3]);
      stage64(Vb + (mt0 + 1) * 64, N_, Vsm[(mt0 + 1) & 3]);
      WAITCNT("vmcnt(8)");                      // Q done; KV batches in flight
    } else {
      WAITCNT("vmcnt(4)");
    }
    SBAR();
    bf16x8 qf[4][2];
#pragma unroll
    for (int ni = 0; ni < 4; ni++) {
      qf[ni][0] = frag_ld(Psm[0], ni * 16 + c, 0);
      qf[ni][1] = frag_ld(Psm[0], ni * 16 + c, 1);
    }
    f32x4 out[4] = {};

#pragma unroll 1
    for (int mt = mt0; mt < NT; mt++) {
      // FIFO: vmcnt(4) leaves only batch mt+1 -> batch mt (and older) landed.
      // lgkmcnt(0): own qf reads / P writes committed before the barrier.
      if (mt + 1 < NT) WAITCNT("vmcnt(4) lgkmcnt(0)");
      else WAITCNT("vmcnt(0) lgkmcnt(0)");
      SBAR();
      if (mt + 2 < NT) {
        stage64(Kb + (size_t)(mt + 2) * 64 * KD_, KD_, Ksm[(mt + 2) % 3]);
        stage64(Vb + (mt + 2) * 64, N_, Vsm[(mt + 2) & 3]);
      }
      qk_tile(mt, qf, mt == mt0);
      if (mt > mt0) pv_tile(mt - 1, out);
    }
    WAITCNT("lgkmcnt(0)");
    SBAR();                                     // last P tile visible
    pv_tile(NT - 1, out);

#pragma unroll
    for (int ni = 0; ni < 4; ni++) {
#pragma unroll
      for (int r = 0; r < 4; r++) {
        const int n = n0 + w * 16 + g * 4 + r;
        attn[((size_t)(b * N_ + n)) * E_ + h * 64 + ni * 16 + c] =
            __float2bfloat16(out[ni][r]);
      }
    }
  }
}

// ---------------------------------------------------------------------------
extern "C" void kernel_launch(void* const* d_in, const int* in_sizes, int n_in,
                              void* d_out, int out_size, void* d_ws, size_t ws_size,
                              hipStream_t stream) {
  (void)in_sizes; (void)n_in; (void)out_size; (void)ws_size;
  const float* x  = (const float*)d_in[0];
  const float* Wq = (const float*)d_in[1];
  const float* bq = (const float*)d_in[2];
  const float* Wk = (const float*)d_in[3];
  const float* bk = (const float*)d_in[4];
  const float* Wv = (const float*)d_in[5];
  const float* bv = (const float*)d_in[6];
  const float* Wp = (const float*)d_in[7];
  const float* bp = (const float*)d_in[8];
  float* out = (float*)d_out;

  const size_t XN = (size_t)M_ * E_;             // 4M elems
  const size_t WN = (size_t)E_ * E_;             // 1M elems
  const size_t HN = (size_t)B_ * H_ * N_ * KD_;  // 4M elems

  bf16* xb   = (bf16*)d_ws;            // reused as attn buffer later
  bf16* wqkv = xb + XN;                // wq|wk|wv contiguous = fused [3E][E]
  bf16* wpb  = wqkv + 3 * WN;
  bf16* Qhd  = wpb + WN;
  bf16* Khd  = Qhd + HN;
  bf16* Vtd  = Khd + HN;
  bf16* attn = xb;                     // xb dead after QKV GEMM

  cvt_all<<<dim3(8192), 256, 0, stream>>>(x, Wq, Wk, Wv, Wp, xb);

  gemm_qkv<<<dim3(24, 32), 256, 0, stream>>>(xb, wqkv, bq, bk, bv,
                                             Qhd, Khd, Vtd);

  phaseA<<<dim3(16, B_ * H_), 256, 0, stream>>>(Khd, Qhd, Vtd);
  phaseB<<<dim3(16, B_ * H_), 256, 0, stream>>>(Qhd, Khd, Vtd, attn);

  gemm_proj<<<dim3(8, 32), 256, 0, stream>>>(attn, wpb, bp, out);
}